// Round 7
// baseline (73.891 us; speedup 1.0000x reference)
//
#include <hip/hip_runtime.h>

// R7 ABLATION ROUND: two dispatches, differencing gives pure-store cost.
//   1) roi_store_probe: IDENTICAL store stream to the real kernel (same grid,
//      same logical->address mapping, same quad dwordx4 stores), junk values,
//      no fm loads / no LDS / no barrier. Measures write-side cost alone.
//   2) roi_align_v6 (unchanged R6): overwrites every output element with the
//      correct values -> final d_out is correct.
// Bench dur_us = T_store + T_full;  T_store = dur_us - 56.8 (R6 baseline).

typedef float f32x4 __attribute__((ext_vector_type(4)));
typedef float f32x2 __attribute__((ext_vector_type(2)));

constexpr int C_DIM = 256;
constexpr int H_DIM = 50;
constexpr int W_DIM = 50;
constexpr int M_BOX = 512;
constexpr int CW    = 14;
constexpr int NPOS  = 196;            // 14*14
constexpr int CCH   = 32;             // channels per block
constexpr int NCHUNK = C_DIM / CCH;   // 8
constexpr int PLANE  = H_DIM * W_DIM; // 2500
constexpr int WC  = 16;               // window cols
constexpr int WSZ = 256;              // 16 rows x 16 cols per plane
constexpr float INV_STRIDE = 1.0f / 16.0f;

// ---------- probe: store stream only ----------
__global__ __launch_bounds__(256) void roi_store_probe(
    const float* __restrict__ boxes,
    float*       __restrict__ out)
{
    int bid     = blockIdx.x;
    int logical = (bid & 7) * ((M_BOX * NCHUNK) / 8) + (bid >> 3);
    int m       = logical >> 3;
    int cbase   = (logical & 7) * CCH;
    int t = threadIdx.x;
    if (t < NPOS) {
        int csub = t / 49;
        int q    = t - csub * 49;
        float4 bx = reinterpret_cast<const float4*>(boxes)[m];
        float v0 = bx.x + (float)t;       // junk, not DCE-able (global store)
        float* op = out + ((size_t)m * C_DIM + cbase + csub * 8) * NPOS + 4 * q;
        #pragma unroll 2
        for (int k = 0; k < 8; ++k) {
            f32x4 r;
            r.x = v0; r.y = v0 + (float)k; r.z = v0 * 0.5f; r.w = v0 - (float)k;
            *reinterpret_cast<f32x4*>(op) = r;
            op += NPOS;
        }
    }
}

// ---------- real kernel: unchanged R6 ----------
__global__ __launch_bounds__(256) void roi_align_v6(
    const float* __restrict__ fm,
    const float* __restrict__ boxes,
    const int*   __restrict__ box_idx,
    float*       __restrict__ out)
{
    __shared__ float Wnd[CCH * WSZ];  // 32 KB

    int bid     = blockIdx.x;
    int logical = (bid & 7) * ((M_BOX * NCHUNK) / 8) + (bid >> 3);
    int m       = logical >> 3;
    int cbase   = (logical & 7) * CCH;

    int t = threadIdx.x;

    float4 bx = reinterpret_cast<const float4*>(boxes)[m];
    int bi = box_idx[m];
    float x1 = bx.x * INV_STRIDE;
    float y1 = bx.y * INV_STRIDE;
    float x2 = bx.z * INV_STRIDE;
    float y2 = bx.w * INV_STRIDE;

    int xLo = min(max((int)floorf(x1), 0), W_DIM - 1);
    int yLo = min(max((int)floorf(y1), 0), H_DIM - 1);
    int xE  = xLo & ~1;

    // ---- Phase A: stage 16x16 window of each of CCH planes ----
    {
        int sub = t & 7;
        int rr  = (t >> 3) & 15;
        int pg  = t >> 7;
        int gy  = min(yLo + rr, H_DIM - 1);
        int gxp = min(xE + sub * 2, W_DIM - 2);
        const float* gsrc = fm + ((size_t)(bi * C_DIM + cbase + pg)) * PLANE
                               + gy * W_DIM + gxp;
        float* ldst = &Wnd[pg * WSZ + rr * WC + sub * 2];
        #pragma unroll
        for (int k = 0; k < CCH / 2; ++k) {
            f32x2 v = *reinterpret_cast<const f32x2*>(gsrc);
            *reinterpret_cast<f32x2*>(ldst) = v;
            gsrc += 2 * (size_t)PLANE;
            ldst += 2 * WSZ;
        }
    }
    __syncthreads();

    // ---- Phase B ----
    if (t < NPOS) {
        int csub = t / 49;
        int q    = t - csub * 49;

        int   w00[4];
        float wxv[4], owx[4], wyv[4], owy[4];
        bool  vld[4];
        #pragma unroll
        for (int e = 0; e < 4; ++e) {
            int p  = 4 * q + e;
            int iy = p / CW;
            int ix = p - iy * CW;
            float ys = y1 + ((float)iy * (y2 - y1)) / 13.0f;
            float xs = x1 + ((float)ix * (x2 - x1)) / 13.0f;
            float y0f = floorf(ys);
            float x0f = floorf(xs);
            float wy = ys - y0f;
            float wx = xs - x0f;
            int y0i = min(max((int)y0f, 0), H_DIM - 1);
            int x0i = min(max((int)x0f, 0), W_DIM - 1);
            vld[e] = (ys >= 0.0f) && (ys <= (float)(H_DIM - 1)) &&
                     (xs >= 0.0f) && (xs <= (float)(W_DIM - 1));
            w00[e] = (y0i - yLo) * WC + (x0i - xE);
            wxv[e] = wx; owx[e] = 1.0f - wx;
            wyv[e] = wy; owy[e] = 1.0f - wy;
        }

        const float* wp = &Wnd[(size_t)csub * 8 * WSZ];
        float* op = out + ((size_t)m * C_DIM + cbase + csub * 8) * NPOS + 4 * q;

        #pragma unroll 2
        for (int k = 0; k < 8; ++k) {
            float rv[4];
            #pragma unroll
            for (int e = 0; e < 4; ++e) {
                float f00 = wp[w00[e]];
                float f01 = wp[w00[e] + 1];
                float f10 = wp[w00[e] + WC];
                float f11 = wp[w00[e] + WC + 1];
                float top = f00 * owx[e] + f01 * wxv[e];
                float bot = f10 * owx[e] + f11 * wxv[e];
                float v   = top * owy[e] + bot * wyv[e];
                rv[e] = vld[e] ? v : 0.0f;
            }
            f32x4 r;
            r.x = rv[0]; r.y = rv[1]; r.z = rv[2]; r.w = rv[3];
            *reinterpret_cast<f32x4*>(op) = r;
            wp += WSZ;
            op += NPOS;
        }
    }
}

extern "C" void kernel_launch(void* const* d_in, const int* in_sizes, int n_in,
                              void* d_out, int out_size, void* d_ws, size_t ws_size,
                              hipStream_t stream) {
    const float* fm      = (const float*)d_in[0];
    const float* boxes   = (const float*)d_in[1];
    const int*   box_idx = (const int*)d_in[2];
    float* out = (float*)d_out;

    dim3 block(256);
    dim3 grid(M_BOX * NCHUNK);  // 4096 blocks

    // 1) store-only probe (junk values; fully overwritten by dispatch 2)
    hipLaunchKernelGGL(roi_store_probe, grid, block, 0, stream, boxes, out);
    // 2) real kernel (correct output)
    hipLaunchKernelGGL(roi_align_v6, grid, block, 0, stream,
                       fm, boxes, box_idx, out);
}

// Round 8
// 56.715 us; speedup vs baseline: 1.3028x; 1.3028x over previous
//
#include <hip/hip_runtime.h>

// RoiAlign: fm (4,256,50,50) f32, boxes (512,4), box_idx (512) -> out (512,256,14,14) f32
//
// R8: attack read-side LATENCY (R7 ablation: store stream alone = 17us = write
// roofline; R6's extra 40us is staging convoy, not any throughput pipe).
//  - Phase A via __builtin_amdgcn_global_load_lds width=16: ONE wave-instr
//    stages ONE plane's 16x16 window (lane l -> row l>>2 [clamp-duplicated],
//    col quad l&3; LDS dst = uniform plane base + lane*16B). 4 instrs/wave,
//    async, no VGPR round trip; the single __syncthreads is the only wait.
//  - CCH=16 planes/block -> 16 KB LDS -> 8 blocks/CU resident (was 5) for TLP.
//  - Window origin xW=min(xLo,34): all global reads in-bounds, no col clamp.
//    Taps at w00+{0,1,16,17}: row duplication makes +16 exact; the col-15 "+1"
//    wrap only happens when wx==0 or the sample is masked invalid (finite junk).
//  - Phase B: thread owns 4 consecutive positions x 4 channels; 2x ds_read2
//    per element; one dwordx4 store per 4 elements (plain stores - L2 merges).
// XCD affinity: all 16 chunks of a box on one XCD (bid%8 partition).

typedef float f32x4 __attribute__((ext_vector_type(4)));

constexpr int C_DIM = 256;
constexpr int H_DIM = 50;
constexpr int W_DIM = 50;
constexpr int M_BOX = 512;
constexpr int CW    = 14;
constexpr int NPOS  = 196;            // 14*14
constexpr int CCH   = 16;             // channels per block
constexpr int NCHUNK = C_DIM / CCH;   // 16
constexpr int PLANE  = H_DIM * W_DIM; // 2500
constexpr int WC  = 16;               // window cols
constexpr int WSZ = 256;              // 16x16 window floats per plane
constexpr float INV_STRIDE = 1.0f / 16.0f;

__global__ __launch_bounds__(256) void roi_align_v8(
    const float* __restrict__ fm,
    const float* __restrict__ boxes,
    const int*   __restrict__ box_idx,
    float*       __restrict__ out)
{
    __shared__ float Wnd[CCH * WSZ];  // 16 KB

    int bid     = blockIdx.x;
    int logical = (bid & 7) * ((M_BOX * NCHUNK) / 8) + (bid >> 3);
    int m       = logical >> 4;
    int cbase   = (logical & 15) * CCH;

    int t = threadIdx.x;

    float4 bx = reinterpret_cast<const float4*>(boxes)[m];
    int bi = box_idx[m];
    float x1 = bx.x * INV_STRIDE;
    float y1 = bx.y * INV_STRIDE;
    float x2 = bx.z * INV_STRIDE;
    float y2 = bx.w * INV_STRIDE;

    int xLo = min(max((int)floorf(x1), 0), W_DIM - 1);
    int yLo = min(max((int)floorf(y1), 0), H_DIM - 1);
    int xW  = min(xLo, W_DIM - WC);   // window cols xW..xW+15 always in-bounds

    // ---- Phase A: async DMA, one wave-instr per plane window ----
    {
        int w    = t >> 6;            // wave 0..3 -> planes 4w..4w+3
        int l    = t & 63;
        int row  = l >> 2;            // 0..15
        int quad = l & 3;             // 0..3 -> cols 4quad..4quad+3
        int gy   = min(yLo + row, H_DIM - 1);   // row clamp-duplicate
        const float* g0 = fm + ((size_t)(bi * C_DIM + cbase + w * 4)) * PLANE
                             + gy * W_DIM + xW + quad * 4;
        #pragma unroll
        for (int k = 0; k < 4; ++k) {
            const float* g  = g0 + (size_t)k * PLANE;
            float*       l0 = &Wnd[(w * 4 + k) * WSZ];   // wave-uniform base
            __builtin_amdgcn_global_load_lds(
                (const __attribute__((address_space(1))) unsigned int*)g,
                (__attribute__((address_space(3))) unsigned int*)l0,
                16, 0, 0);
        }
    }
    __syncthreads();   // drains vmcnt(0) -- the one wait we actually need

    // ---- Phase B: 4 positions x 4 channels per thread ----
    if (t < NPOS) {
        int csub = t / 49;        // 0..3 -> channels csub*4 .. csub*4+3
        int q    = t - csub * 49; // 0..48 -> positions 4q..4q+3

        int   w00[4];
        float wxv[4], owx[4], wyv[4], owy[4];
        bool  vld[4];
        #pragma unroll
        for (int e = 0; e < 4; ++e) {
            int p  = 4 * q + e;
            int iy = p / CW;
            int ix = p - iy * CW;
            // reference op order: v1 + (i * (v2-v1)) / 13
            float ys = y1 + ((float)iy * (y2 - y1)) / 13.0f;
            float xs = x1 + ((float)ix * (x2 - x1)) / 13.0f;
            float y0f = floorf(ys);
            float x0f = floorf(xs);
            float wy = ys - y0f;
            float wx = xs - x0f;
            int y0i = min(max((int)y0f, 0), H_DIM - 1);
            int x0i = min(max((int)x0f, 0), W_DIM - 1);
            vld[e] = (ys >= 0.0f) && (ys <= (float)(H_DIM - 1)) &&
                     (xs >= 0.0f) && (xs <= (float)(W_DIM - 1));
            w00[e] = (y0i - yLo) * WC + (x0i - xW);
            wxv[e] = wx; owx[e] = 1.0f - wx;
            wyv[e] = wy; owy[e] = 1.0f - wy;
        }

        const float* wp = &Wnd[(size_t)csub * 4 * WSZ];
        float* op = out + ((size_t)m * C_DIM + cbase + csub * 4) * NPOS + 4 * q;

        #pragma unroll
        for (int k = 0; k < 4; ++k) {
            float rv[4];
            #pragma unroll
            for (int e = 0; e < 4; ++e) {
                float f00 = wp[w00[e]];
                float f01 = wp[w00[e] + 1];
                float f10 = wp[w00[e] + WC];
                float f11 = wp[w00[e] + WC + 1];
                float top = f00 * owx[e] + f01 * wxv[e];
                float bot = f10 * owx[e] + f11 * wxv[e];
                float v   = top * owy[e] + bot * wyv[e];
                rv[e] = vld[e] ? v : 0.0f;
            }
            f32x4 r;
            r.x = rv[0]; r.y = rv[1]; r.z = rv[2]; r.w = rv[3];
            *reinterpret_cast<f32x4*>(op) = r;
            wp += WSZ;
            op += NPOS;
        }
    }
}

extern "C" void kernel_launch(void* const* d_in, const int* in_sizes, int n_in,
                              void* d_out, int out_size, void* d_ws, size_t ws_size,
                              hipStream_t stream) {
    const float* fm      = (const float*)d_in[0];
    const float* boxes   = (const float*)d_in[1];
    const int*   box_idx = (const int*)d_in[2];
    float* out = (float*)d_out;

    dim3 block(256);
    dim3 grid(M_BOX * NCHUNK);  // 8192 blocks
    hipLaunchKernelGGL(roi_align_v8, grid, block, 0, stream,
                       fm, boxes, box_idx, out);
}

// Round 9
// 30.984 us; speedup vs baseline: 2.3848x; 1.8305x over previous
//
#include <hip/hip_runtime.h>

// RoiAlign: fm (4,256,50,50) f32, boxes (512,4), box_idx (512) -> out (512,256,14,14) f32
//
// R9: channel-slab XCD tiling. R7 ablation: store stream alone = 17us (write
// roofline). R2/R3/R4b/R6/R8 (five different read mechanisms) all pay ~38us
// more => the cost is the READ DEMAND vs the cache hierarchy, not any CU pipe:
// per-XCD working set (64 boxes x 256 ch windows ~ 6MB) > 4MB L2 -> thrash ->
// ~128MB of re-reads served by the slow L3 path.
// Fix: XCD k owns channel slab [32k, 32k+32) for ALL 512 boxes. Slab = 32ch x
// 4img x 10KB = 1.28MB -> L2-resident. fm leaves HBM/L3 once (10MB); re-reads
// hit own-XCD L2.
// Mechanics otherwise identical to R8:
//  - Phase A: one __builtin_amdgcn_global_load_lds(16B) stages one plane's
//    16x16 window per wave-instr (row clamp-duplicated), async until barrier.
//  - Phase B: taps at w00+{0,1,16,17} (ds_read2), quad dwordx4 plain stores.

typedef float f32x4 __attribute__((ext_vector_type(4)));

constexpr int C_DIM = 256;
constexpr int H_DIM = 50;
constexpr int W_DIM = 50;
constexpr int M_BOX = 512;
constexpr int CW    = 14;
constexpr int NPOS  = 196;            // 14*14
constexpr int CCH   = 16;             // channels per block
constexpr int PLANE  = H_DIM * W_DIM; // 2500
constexpr int WC  = 16;               // window cols
constexpr int WSZ = 256;              // 16x16 window floats per plane
constexpr float INV_STRIDE = 1.0f / 16.0f;

__global__ __launch_bounds__(256) void roi_align_v9(
    const float* __restrict__ fm,
    const float* __restrict__ boxes,
    const int*   __restrict__ box_idx,
    float*       __restrict__ out)
{
    __shared__ float Wnd[CCH * WSZ];  // 16 KB -> 8 blocks/CU

    // Channel-slab XCD mapping: dispatch sends bid -> XCD (bid % 8).
    // XCD k handles channels [32k, 32k+32) for all boxes:
    //   within-XCD index w = bid>>3 in [0,1024): box = w>>1, half-slab = w&1.
    int bid   = blockIdx.x;
    int xcd   = bid & 7;
    int w     = bid >> 3;
    int m     = w >> 1;
    int cbase = xcd * 32 + (w & 1) * CCH;

    int t = threadIdx.x;

    float4 bx = reinterpret_cast<const float4*>(boxes)[m];
    int bi = box_idx[m];
    float x1 = bx.x * INV_STRIDE;
    float y1 = bx.y * INV_STRIDE;
    float x2 = bx.z * INV_STRIDE;
    float y2 = bx.w * INV_STRIDE;

    int xLo = min(max((int)floorf(x1), 0), W_DIM - 1);
    int yLo = min(max((int)floorf(y1), 0), H_DIM - 1);
    int xW  = min(xLo, W_DIM - WC);   // window cols xW..xW+15 always in-bounds

    // ---- Phase A: async DMA, one wave-instr per plane window ----
    {
        int wv   = t >> 6;            // wave 0..3 -> planes 4wv..4wv+3
        int l    = t & 63;
        int row  = l >> 2;            // 0..15
        int quad = l & 3;             // 0..3 -> cols 4quad..4quad+3
        int gy   = min(yLo + row, H_DIM - 1);   // row clamp-duplicate
        const float* g0 = fm + ((size_t)(bi * C_DIM + cbase + wv * 4)) * PLANE
                             + gy * W_DIM + xW + quad * 4;
        #pragma unroll
        for (int k = 0; k < 4; ++k) {
            const float* g  = g0 + (size_t)k * PLANE;
            float*       l0 = &Wnd[(wv * 4 + k) * WSZ];  // wave-uniform base
            __builtin_amdgcn_global_load_lds(
                (const __attribute__((address_space(1))) unsigned int*)g,
                (__attribute__((address_space(3))) unsigned int*)l0,
                16, 0, 0);
        }
    }
    __syncthreads();

    // ---- Phase B: 4 positions x 4 channels per thread ----
    if (t < NPOS) {
        int csub = t / 49;        // 0..3 -> channels csub*4 .. csub*4+3
        int q    = t - csub * 49; // 0..48 -> positions 4q..4q+3

        int   w00[4];
        float wxv[4], owx[4], wyv[4], owy[4];
        bool  vld[4];
        #pragma unroll
        for (int e = 0; e < 4; ++e) {
            int p  = 4 * q + e;
            int iy = p / CW;
            int ix = p - iy * CW;
            // reference op order: v1 + (i * (v2-v1)) / 13
            float ys = y1 + ((float)iy * (y2 - y1)) / 13.0f;
            float xs = x1 + ((float)ix * (x2 - x1)) / 13.0f;
            float y0f = floorf(ys);
            float x0f = floorf(xs);
            float wy = ys - y0f;
            float wx = xs - x0f;
            int y0i = min(max((int)y0f, 0), H_DIM - 1);
            int x0i = min(max((int)x0f, 0), W_DIM - 1);
            vld[e] = (ys >= 0.0f) && (ys <= (float)(H_DIM - 1)) &&
                     (xs >= 0.0f) && (xs <= (float)(W_DIM - 1));
            w00[e] = (y0i - yLo) * WC + (x0i - xW);
            wxv[e] = wx; owx[e] = 1.0f - wx;
            wyv[e] = wy; owy[e] = 1.0f - wy;
        }

        const float* wp = &Wnd[(size_t)csub * 4 * WSZ];
        float* op = out + ((size_t)m * C_DIM + cbase + csub * 4) * NPOS + 4 * q;

        #pragma unroll
        for (int k = 0; k < 4; ++k) {
            float rv[4];
            #pragma unroll
            for (int e = 0; e < 4; ++e) {
                float f00 = wp[w00[e]];
                float f01 = wp[w00[e] + 1];
                float f10 = wp[w00[e] + WC];
                float f11 = wp[w00[e] + WC + 1];
                float top = f00 * owx[e] + f01 * wxv[e];
                float bot = f10 * owx[e] + f11 * wxv[e];
                float v   = top * owy[e] + bot * wyv[e];
                rv[e] = vld[e] ? v : 0.0f;
            }
            f32x4 r;
            r.x = rv[0]; r.y = rv[1]; r.z = rv[2]; r.w = rv[3];
            *reinterpret_cast<f32x4*>(op) = r;
            wp += WSZ;
            op += NPOS;
        }
    }
}

extern "C" void kernel_launch(void* const* d_in, const int* in_sizes, int n_in,
                              void* d_out, int out_size, void* d_ws, size_t ws_size,
                              hipStream_t stream) {
    const float* fm      = (const float*)d_in[0];
    const float* boxes   = (const float*)d_in[1];
    const int*   box_idx = (const int*)d_in[2];
    float* out = (float*)d_out;

    dim3 block(256);
    dim3 grid(M_BOX * (C_DIM / CCH) /* 8192 */);
    hipLaunchKernelGGL(roi_align_v9, grid, block, 0, stream,
                       fm, boxes, box_idx, out);
}

// Round 10
// 30.105 us; speedup vs baseline: 2.4545x; 1.0292x over previous
//
#include <hip/hip_runtime.h>

// RoiAlign: fm (4,256,50,50) f32, boxes (512,4), box_idx (512) -> out (512,256,14,14) f32
//
// R10: wave-autonomous staging (no __syncthreads).
// Keeps R9's winning channel-slab XCD tiling (XCD k owns channels [32k,32k+32)
// for ALL boxes -> 1.28 MB L2-resident slab; R9: 56.7 -> 31.0 us).
// New: each WAVE stages exactly the 4 planes its own lanes read:
//   - wave wv issues 4 global_load_lds(16B) for channels cbase+4wv..+3
//     (lane l -> row l>>2 clamp-duplicated, col-quad l&3; dst uniform+lane*16B)
//   - waits on ITS OWN vmcnt(0) via inline asm -- no cross-wave barrier drain,
//     no lockstep; waves drift and pipeline each other's latency.
//   - Phase B: lanes 0..48 own one position-quad, loop the wave's 4 channels;
//     taps at w00+{0,1,16,17} (ds_read2); one dwordx4 plain store per 4 elems.
// Validity folded into x-weights at setup (invalid -> wx=owx=0 -> exact 0),
// removing per-element cndmasks.

typedef float f32x4 __attribute__((ext_vector_type(4)));

constexpr int C_DIM = 256;
constexpr int H_DIM = 50;
constexpr int W_DIM = 50;
constexpr int M_BOX = 512;
constexpr int CW    = 14;
constexpr int NPOS  = 196;            // 14*14
constexpr int CCH   = 16;             // channels per block (4 waves x 4)
constexpr int PLANE  = H_DIM * W_DIM; // 2500
constexpr int WC  = 16;               // window cols
constexpr int WSZ = 256;              // 16x16 window floats per plane
constexpr float INV_STRIDE = 1.0f / 16.0f;

__global__ __launch_bounds__(256) void roi_align_v10(
    const float* __restrict__ fm,
    const float* __restrict__ boxes,
    const int*   __restrict__ box_idx,
    float*       __restrict__ out)
{
    __shared__ float Wnd[CCH * WSZ];  // 16 KB -> 8 blocks/CU

    // Channel-slab XCD mapping (R9): XCD k = bid&7 owns channels [32k, 32k+32).
    int bid   = blockIdx.x;
    int xcd   = bid & 7;
    int w     = bid >> 3;             // [0,1024)
    int m     = w >> 1;               // box
    int cbase = xcd * 32 + (w & 1) * CCH;

    int t  = threadIdx.x;
    int wv = t >> 6;                  // wave 0..3 -> channels cbase+4wv..+3
    int l  = t & 63;

    float4 bx = reinterpret_cast<const float4*>(boxes)[m];
    int bi = box_idx[m];
    float x1 = bx.x * INV_STRIDE;
    float y1 = bx.y * INV_STRIDE;
    float x2 = bx.z * INV_STRIDE;
    float y2 = bx.w * INV_STRIDE;

    int xLo = min(max((int)floorf(x1), 0), W_DIM - 1);
    int yLo = min(max((int)floorf(y1), 0), H_DIM - 1);
    int xW  = min(xLo, W_DIM - WC);   // window cols xW..xW+15 always in-bounds

    // ---- Phase A: wave stages ITS OWN 4 plane-windows (async DMA) ----
    {
        int row  = l >> 2;            // 0..15
        int quad = l & 3;             // cols 4quad..4quad+3
        int gy   = min(yLo + row, H_DIM - 1);   // row clamp-duplicate
        const float* g0 = fm + ((size_t)(bi * C_DIM + cbase + wv * 4)) * PLANE
                             + gy * W_DIM + xW + quad * 4;
        #pragma unroll
        for (int k = 0; k < 4; ++k) {
            const float* g  = g0 + (size_t)k * PLANE;
            float*       l0 = &Wnd[(wv * 4 + k) * WSZ];  // wave-uniform base
            __builtin_amdgcn_global_load_lds(
                (const __attribute__((address_space(1))) unsigned int*)g,
                (__attribute__((address_space(3))) unsigned int*)l0,
                16, 0, 0);
        }
    }

    // ---- Phase B: lanes 0..48 each own a position-quad x wave's 4 channels ----
    if (l < 49) {
        int q = l;                    // quad -> positions 4q..4q+3

        int   w00[4];
        float wxv[4], owx[4], wyv[4], owy[4];
        #pragma unroll
        for (int e = 0; e < 4; ++e) {
            int p  = 4 * q + e;
            int iy = p / CW;
            int ix = p - iy * CW;
            // reference op order: v1 + (i * (v2-v1)) / 13
            float ys = y1 + ((float)iy * (y2 - y1)) / 13.0f;
            float xs = x1 + ((float)ix * (x2 - x1)) / 13.0f;
            float y0f = floorf(ys);
            float x0f = floorf(xs);
            float wy = ys - y0f;
            float wx = xs - x0f;
            int y0i = min(max((int)y0f, 0), H_DIM - 1);
            int x0i = min(max((int)x0f, 0), W_DIM - 1);
            bool vld = (ys >= 0.0f) && (ys <= (float)(H_DIM - 1)) &&
                       (xs >= 0.0f) && (xs <= (float)(W_DIM - 1));
            w00[e] = (y0i - yLo) * WC + (x0i - xW);
            // fold validity into x-weights: invalid -> both 0 -> result exact 0
            wxv[e] = vld ? wx : 0.0f;
            owx[e] = vld ? (1.0f - wx) : 0.0f;
            wyv[e] = wy; owy[e] = 1.0f - wy;
        }

        // wait for THIS WAVE's 4 DMA loads only (no cross-wave drain);
        // setup above overlapped the DMA flight time.
        asm volatile("s_waitcnt vmcnt(0)" ::: "memory");

        const float* wp = &Wnd[(size_t)(wv * 4) * WSZ];
        float* op = out + ((size_t)m * C_DIM + cbase + wv * 4) * NPOS + 4 * q;

        #pragma unroll
        for (int k = 0; k < 4; ++k) {
            float rv[4];
            #pragma unroll
            for (int e = 0; e < 4; ++e) {
                float f00 = wp[w00[e]];
                float f01 = wp[w00[e] + 1];
                float f10 = wp[w00[e] + WC];
                float f11 = wp[w00[e] + WC + 1];
                float top = f00 * owx[e] + f01 * wxv[e];
                float bot = f10 * owx[e] + f11 * wxv[e];
                rv[e] = top * owy[e] + bot * wyv[e];
            }
            f32x4 r;
            r.x = rv[0]; r.y = rv[1]; r.z = rv[2]; r.w = rv[3];
            *reinterpret_cast<f32x4*>(op) = r;   // plain store (L2 merges)
            wp += WSZ;
            op += NPOS;
        }
    }
}

extern "C" void kernel_launch(void* const* d_in, const int* in_sizes, int n_in,
                              void* d_out, int out_size, void* d_ws, size_t ws_size,
                              hipStream_t stream) {
    const float* fm      = (const float*)d_in[0];
    const float* boxes   = (const float*)d_in[1];
    const int*   box_idx = (const int*)d_in[2];
    float* out = (float*)d_out;

    dim3 block(256);
    dim3 grid(M_BOX * (C_DIM / CCH) /* 8192 */);
    hipLaunchKernelGGL(roi_align_v10, grid, block, 0, stream,
                       fm, boxes, box_idx, out);
}

// Round 11
// 29.953 us; speedup vs baseline: 2.4669x; 1.0051x over previous
//
#include <hip/hip_runtime.h>

// RoiAlign: fm (4,256,50,50) f32, boxes (512,4), box_idx (512) -> out (512,256,14,14) f32
//
// R11: == R10 EXCEPT nontemporal output stores.
// Theory: per-XCD, ~12.5 MB of streaming output writes flow through the 4 MB
// L2 with write-allocate, continuously evicting the 1.28 MB fm channel-slab
// that R9's win (56.7->31.0us) established. A fraction of the ~131 MB window
// re-read demand then falls to the slow L3 path. NT stores don't allocate in
// L2 -> slab stays resident -> reads stay at L2 speed.
// (R5/R6 NT-vs-plain was neutral, but that was pre-slab when reads thrashed
// regardless; the regime changed, so this is a new A/B.)
// Everything else identical to R10:
//  - R9 channel-slab XCD tiling: XCD k owns channels [32k,32k+32) for ALL boxes.
//  - Wave-autonomous staging: wave stages its own 4 plane-windows via
//    global_load_lds(16B), waits on own vmcnt(0), no __syncthreads.
//  - Taps at w00+{0,1,16,17}; validity folded into x-weights; quad dwordx4 NT
//    stores.

typedef float f32x4 __attribute__((ext_vector_type(4)));

constexpr int C_DIM = 256;
constexpr int H_DIM = 50;
constexpr int W_DIM = 50;
constexpr int M_BOX = 512;
constexpr int CW    = 14;
constexpr int NPOS  = 196;            // 14*14
constexpr int CCH   = 16;             // channels per block (4 waves x 4)
constexpr int PLANE  = H_DIM * W_DIM; // 2500
constexpr int WC  = 16;               // window cols
constexpr int WSZ = 256;              // 16x16 window floats per plane
constexpr float INV_STRIDE = 1.0f / 16.0f;

__global__ __launch_bounds__(256) void roi_align_v11(
    const float* __restrict__ fm,
    const float* __restrict__ boxes,
    const int*   __restrict__ box_idx,
    float*       __restrict__ out)
{
    __shared__ float Wnd[CCH * WSZ];  // 16 KB -> 8 blocks/CU

    // Channel-slab XCD mapping (R9): XCD k = bid&7 owns channels [32k, 32k+32).
    int bid   = blockIdx.x;
    int xcd   = bid & 7;
    int w     = bid >> 3;             // [0,1024)
    int m     = w >> 1;               // box
    int cbase = xcd * 32 + (w & 1) * CCH;

    int t  = threadIdx.x;
    int wv = t >> 6;                  // wave 0..3 -> channels cbase+4wv..+3
    int l  = t & 63;

    float4 bx = reinterpret_cast<const float4*>(boxes)[m];
    int bi = box_idx[m];
    float x1 = bx.x * INV_STRIDE;
    float y1 = bx.y * INV_STRIDE;
    float x2 = bx.z * INV_STRIDE;
    float y2 = bx.w * INV_STRIDE;

    int xLo = min(max((int)floorf(x1), 0), W_DIM - 1);
    int yLo = min(max((int)floorf(y1), 0), H_DIM - 1);
    int xW  = min(xLo, W_DIM - WC);   // window cols xW..xW+15 always in-bounds

    // ---- Phase A: wave stages ITS OWN 4 plane-windows (async DMA) ----
    {
        int row  = l >> 2;            // 0..15
        int quad = l & 3;             // cols 4quad..4quad+3
        int gy   = min(yLo + row, H_DIM - 1);   // row clamp-duplicate
        const float* g0 = fm + ((size_t)(bi * C_DIM + cbase + wv * 4)) * PLANE
                             + gy * W_DIM + xW + quad * 4;
        #pragma unroll
        for (int k = 0; k < 4; ++k) {
            const float* g  = g0 + (size_t)k * PLANE;
            float*       l0 = &Wnd[(wv * 4 + k) * WSZ];  // wave-uniform base
            __builtin_amdgcn_global_load_lds(
                (const __attribute__((address_space(1))) unsigned int*)g,
                (__attribute__((address_space(3))) unsigned int*)l0,
                16, 0, 0);
        }
    }

    // ---- Phase B: lanes 0..48 each own a position-quad x wave's 4 channels ----
    if (l < 49) {
        int q = l;                    // quad -> positions 4q..4q+3

        int   w00[4];
        float wxv[4], owx[4], wyv[4], owy[4];
        #pragma unroll
        for (int e = 0; e < 4; ++e) {
            int p  = 4 * q + e;
            int iy = p / CW;
            int ix = p - iy * CW;
            // reference op order: v1 + (i * (v2-v1)) / 13
            float ys = y1 + ((float)iy * (y2 - y1)) / 13.0f;
            float xs = x1 + ((float)ix * (x2 - x1)) / 13.0f;
            float y0f = floorf(ys);
            float x0f = floorf(xs);
            float wy = ys - y0f;
            float wx = xs - x0f;
            int y0i = min(max((int)y0f, 0), H_DIM - 1);
            int x0i = min(max((int)x0f, 0), W_DIM - 1);
            bool vld = (ys >= 0.0f) && (ys <= (float)(H_DIM - 1)) &&
                       (xs >= 0.0f) && (xs <= (float)(W_DIM - 1));
            w00[e] = (y0i - yLo) * WC + (x0i - xW);
            // fold validity into x-weights: invalid -> both 0 -> result exact 0
            wxv[e] = vld ? wx : 0.0f;
            owx[e] = vld ? (1.0f - wx) : 0.0f;
            wyv[e] = wy; owy[e] = 1.0f - wy;
        }

        // wait for THIS WAVE's 4 DMA loads only (no cross-wave drain)
        asm volatile("s_waitcnt vmcnt(0)" ::: "memory");

        const float* wp = &Wnd[(size_t)(wv * 4) * WSZ];
        float* op = out + ((size_t)m * C_DIM + cbase + wv * 4) * NPOS + 4 * q;

        #pragma unroll
        for (int k = 0; k < 4; ++k) {
            float rv[4];
            #pragma unroll
            for (int e = 0; e < 4; ++e) {
                float f00 = wp[w00[e]];
                float f01 = wp[w00[e] + 1];
                float f10 = wp[w00[e] + WC];
                float f11 = wp[w00[e] + WC + 1];
                float top = f00 * owx[e] + f01 * wxv[e];
                float bot = f10 * owx[e] + f11 * wxv[e];
                rv[e] = top * owy[e] + bot * wyv[e];
            }
            f32x4 r;
            r.x = rv[0]; r.y = rv[1]; r.z = rv[2]; r.w = rv[3];
            __builtin_nontemporal_store(r, reinterpret_cast<f32x4*>(op));
            wp += WSZ;
            op += NPOS;
        }
    }
}

extern "C" void kernel_launch(void* const* d_in, const int* in_sizes, int n_in,
                              void* d_out, int out_size, void* d_ws, size_t ws_size,
                              hipStream_t stream) {
    const float* fm      = (const float*)d_in[0];
    const float* boxes   = (const float*)d_in[1];
    const int*   box_idx = (const int*)d_in[2];
    float* out = (float*)d_out;

    dim3 block(256);
    dim3 grid(M_BOX * (C_DIM / CCH) /* 8192 */);
    hipLaunchKernelGGL(roi_align_v11, grid, block, 0, stream,
                       fm, boxes, box_idx, out);
}